// Round 17
// baseline (652.544 us; speedup 1.0000x reference)
//
#include <hip/hip_runtime.h>
#include <hip/hip_bf16.h>
#include <math.h>

#define BB 2
#define SS 4096
#define DD 768
#define HH 12
#define DHH 64
#define WW 256
#define CC 16
#define FF 3072

typedef __attribute__((ext_vector_type(8))) short bf16x8;
typedef __attribute__((ext_vector_type(4))) float f32x4;

struct TP12 { const float* s[12]; unsigned short* d[12]; };
struct TP4  { const float* s[4];  unsigned short* d[4];  };

// gelu(x) = 0.5x(1+tanh(u)) = x * sigmoid(2u), u = 0.79788456(x + 0.044715 x^3)
__device__ __forceinline__ float gelu_f(float x) {
    float u = 0.7978845608028654f * fmaf(0.044715f * x * x, x, x);
    return x / (1.f + __expf(-2.f * u));
}

__device__ __forceinline__ unsigned short bfb(float f) {
    __hip_bfloat16 h = __float2bfloat16(f);
    return *(unsigned short*)&h;
}

__device__ __forceinline__ float bf2f(unsigned short u) {
    return __uint_as_float(((unsigned int)u) << 16);
}

__device__ __forceinline__ void gload16(const void* g, void* l) {
    __builtin_amdgcn_global_load_lds(
        (const __attribute__((address_space(1))) unsigned int*)g,
        (__attribute__((address_space(3))) unsigned int*)l, 16, 0, 0);
}

// ---------------- fused weight transposes: fp32 [K][N] -> bf16 [N][K] ----------------
__global__ __launch_bounds__(256) void transpose12_k(TP12 p)
{
    __shared__ float t[32][33];
    int z = blockIdx.z;
    const float* Wsrc = p.s[z];
    unsigned short* Wt = p.d[z];
    const int K = DD, N = DD;
    int n0 = blockIdx.x * 32, k0 = blockIdx.y * 32;
    int tx = threadIdx.x & 31, ty = threadIdx.x >> 5;
#pragma unroll
    for (int i = 0; i < 32; i += 8)
        t[ty + i][tx] = Wsrc[(size_t)(k0 + ty + i) * N + n0 + tx];
    __syncthreads();
#pragma unroll
    for (int i = 0; i < 32; i += 8)
        Wt[(size_t)(n0 + ty + i) * K + k0 + tx] = bfb(t[tx][ty + i]);
}

__global__ __launch_bounds__(256) void transposeR4_k(TP4 p)
{
    __shared__ float t[32][33];
    int z = blockIdx.z;
    const float* Wsrc = p.s[z];
    unsigned short* Wt = p.d[z];
    int K, N, n0, k0;
    if (z < 2) { K = DD; N = FF; n0 = blockIdx.x * 32; k0 = blockIdx.y * 32; }
    else { K = FF; N = DD; int cell = blockIdx.y * 96 + blockIdx.x;
           n0 = (cell % 24) * 32; k0 = (cell / 24) * 32; }
    int tx = threadIdx.x & 31, ty = threadIdx.x >> 5;
#pragma unroll
    for (int i = 0; i < 32; i += 8)
        t[ty + i][tx] = Wsrc[(size_t)(k0 + ty + i) * N + n0 + tx];
    __syncthreads();
#pragma unroll
    for (int i = 0; i < 32; i += 8)
        Wt[(size_t)(n0 + ty + i) * K + k0 + tx] = bfb(t[tx][ty + i]);
}

// ---------------- pack 5 bias vectors [2][768] each -> [2][3840] ----------------
__global__ __launch_bounds__(256) void pack_bias5_k(const float* __restrict__ b0,
        const float* __restrict__ b1, const float* __restrict__ b2,
        const float* __restrict__ b3, const float* __restrict__ b4,
        float* __restrict__ dst)
{
    int gid = blockIdx.x * 256 + threadIdx.x;
    if (gid >= 2 * 5 * DD) return;
    int l = gid / (5 * DD), r = gid % (5 * DD), seg = r / DD, i = r % DD;
    const float* srcs[5] = { b0, b1, b2, b3, b4 };
    dst[gid] = srcs[seg][l * DD + i];
}

// ---------------- embedding + LayerNorm (bf16 activation stream only) ----------------
__global__ __launch_bounds__(256) void embed_ln_k(const int* __restrict__ ids,
        const float* __restrict__ wemb, const float* __restrict__ pemb,
        const float* __restrict__ g, const float* __restrict__ bta,
        unsigned short* __restrict__ xbf)
{
    int row = blockIdx.x;
    int s = row & (SS - 1);
    int tid = threadIdx.x;
    int lane = tid & 63, wvi = tid >> 6;
    __shared__ float red[8];
    float4 v = { 0.f, 0.f, 0.f, 0.f };
    if (tid < 192) {
        const float4* we = (const float4*)(wemb + (size_t)ids[row] * DD);
        const float4* pe = (const float4*)(pemb + (size_t)s * DD);
        float4 a = we[tid], b = pe[tid];
        v.x = a.x + b.x; v.y = a.y + b.y; v.z = a.z + b.z; v.w = a.w + b.w;
    }
    float sum = (v.x + v.y) + (v.z + v.w);
    float sq = fmaf(v.x, v.x, fmaf(v.y, v.y, fmaf(v.z, v.z, v.w * v.w)));
#pragma unroll
    for (int o = 1; o < 64; o <<= 1) {
        sum += __shfl_xor(sum, o);
        sq  += __shfl_xor(sq, o);
    }
    if (lane == 0) { red[wvi] = sum; red[4 + wvi] = sq; }
    __syncthreads();
    float S = (red[0] + red[1]) + (red[2] + red[3]);
    float Q = (red[4] + red[5]) + (red[6] + red[7]);
    float mean = S * (1.f / DD);
    float var = Q * (1.f / DD) - mean * mean;
    float rstd = rsqrtf(var + 1e-5f);
    if (tid < 192) {
        float4 gg = ((const float4*)g)[tid];
        float4 bb = ((const float4*)bta)[tid];
        float4 o;
        o.x = (v.x - mean) * rstd * gg.x + bb.x;
        o.y = (v.y - mean) * rstd * gg.y + bb.y;
        o.z = (v.z - mean) * rstd * gg.z + bb.z;
        o.w = (v.w - mean) * rstd * gg.w + bb.w;
        ushort4 ob = { bfb(o.x), bfb(o.y), bfb(o.z), bfb(o.w) };
        ((ushort4*)(xbf + (size_t)row * DD))[tid] = ob;
    }
}

// ---------------- single-input LayerNorm, bf16 in / bf16 out ----------------
__global__ __launch_bounds__(256) void ln_k(const unsigned short* __restrict__ hin,
        const float* __restrict__ g, const float* __restrict__ bta,
        unsigned short* __restrict__ xbf)
{
    int row = blockIdx.x;
    int tid = threadIdx.x;
    int lane = tid & 63, wvi = tid >> 6;
    __shared__ float red[8];
    float4 v = { 0.f, 0.f, 0.f, 0.f };
    if (tid < 192) {
        ushort4 hv = ((const ushort4*)(hin + (size_t)row * DD))[tid];
        v.x = bf2f(hv.x); v.y = bf2f(hv.y); v.z = bf2f(hv.z); v.w = bf2f(hv.w);
    }
    float sum = (v.x + v.y) + (v.z + v.w);
    float sq = fmaf(v.x, v.x, fmaf(v.y, v.y, fmaf(v.z, v.z, v.w * v.w)));
#pragma unroll
    for (int o = 1; o < 64; o <<= 1) {
        sum += __shfl_xor(sum, o);
        sq  += __shfl_xor(sq, o);
    }
    if (lane == 0) { red[wvi] = sum; red[4 + wvi] = sq; }
    __syncthreads();
    float S = (red[0] + red[1]) + (red[2] + red[3]);
    float Q = (red[4] + red[5]) + (red[6] + red[7]);
    float mean = S * (1.f / DD);
    float var = Q * (1.f / DD) - mean * mean;
    float rstd = rsqrtf(var + 1e-5f);
    if (tid < 192) {
        float4 gg = ((const float4*)g)[tid];
        float4 bb = ((const float4*)bta)[tid];
        float4 o;
        o.x = (v.x - mean) * rstd * gg.x + bb.x;
        o.y = (v.y - mean) * rstd * gg.y + bb.y;
        o.z = (v.z - mean) * rstd * gg.z + bb.z;
        o.w = (v.w - mean) * rstd * gg.w + bb.w;
        ushort4 ob = { bfb(o.x), bfb(o.y), bfb(o.z), bfb(o.w) };
        ((ushort4*)(xbf + (size_t)row * DD))[tid] = ob;
    }
}

// ---------------- 128-tile bf16 MFMA GEMM, BK=64, XOR-swizzled LDS, bn-fast L2 tiling,
// dbuf + counted-vmcnt pipeline; optional fused bf16-residual add; optional fused
// V head-transpose (VT_FUSE: cols [1536,2304) write vt[(b*H+h)*64+d][s] as ushort4). ----------------
template<int OUT_BF16, int ACT_GELU, int ADD_RES, int VT_FUSE>
__global__ __launch_bounds__(256) void mfma_gemm_k(
        const unsigned short* __restrict__ A,
        const unsigned short* __restrict__ Bt,
        const float* __restrict__ bias,
        const unsigned short* __restrict__ xres,
        unsigned short* __restrict__ vtv,
        void* __restrict__ Cv, int M, int N, int K)
{
    __shared__ short As[2 * 128 * 64];
    __shared__ short Bs[2 * 128 * 64];
    const int tid = threadIdx.x;
    const int lane = tid & 63, wv = tid >> 6;
    int nbx = gridDim.x;
    int nby = gridDim.y;
    int nwg = nbx * nby;
    int lid = blockIdx.y * nbx + blockIdx.x;
    int nid = ((nwg & 7) == 0) ? ((lid & 7) * (nwg >> 3) + (lid >> 3)) : lid;
    const int bm = (nid / nby) * 128, bn = (nid % nby) * 128;
    const int wm = wv >> 1, wn = wv & 1;

    const int srow0 = (tid * 16) >> 7;
    const int sbc   = (tid * 16) & 127;
    const int srcc  = sbc ^ ((srow0 & 7) << 4);
    const int ldst  = tid * 16;
    const char* Ab = (const char*)(A + (size_t)bm * K);
    const char* Bb = (const char*)(Bt + (size_t)bn * K);

    f32x4 acc[4][4];
#pragma unroll
    for (int i = 0; i < 4; i++)
#pragma unroll
        for (int j = 0; j < 4; j++) acc[i][j] = (f32x4){0.f, 0.f, 0.f, 0.f};

    const int lr = lane & 15;
    const int g = lane >> 4;
    const int rswz = (lr & 7) << 4;
    const int NK = K >> 6;

    auto stage = [&](int ib, int t) {
        const int k0 = t << 6;
        char* Ad = (char*)As + ib * 16384;
        char* Bd = (char*)Bs + ib * 16384;
#pragma unroll
        for (int p = 0; p < 4; p++) {
            size_t roff = (size_t)(srow0 + p * 32) * (K * 2) + (size_t)k0 * 2 + srcc;
            gload16(Ab + roff, Ad + p * 4096 + ldst);
            gload16(Bb + roff, Bd + p * 4096 + ldst);
        }
    };

    stage(0, 0);

    int cur = 0;
    for (int t = 0; t < NK; t++) {
        if (t + 1 < NK) {
            stage(cur ^ 1, t + 1);
            asm volatile("s_waitcnt vmcnt(8)" ::: "memory");
        } else {
            asm volatile("s_waitcnt vmcnt(0)" ::: "memory");
        }
        __builtin_amdgcn_sched_barrier(0);
        __builtin_amdgcn_s_barrier();
        __builtin_amdgcn_sched_barrier(0);

        const char* Ar = (const char*)As + cur * 16384;
        const char* Br = (const char*)Bs + cur * 16384;
#pragma unroll
        for (int kk = 0; kk < 2; kk++) {
            int colb = (kk * 64 + g * 16) ^ rswz;
            bf16x8 af[4], bfr[4];
#pragma unroll
            for (int i = 0; i < 4; i++)
                af[i] = *(const bf16x8*)(Ar + (wm * 64 + i * 16 + lr) * 128 + colb);
#pragma unroll
            for (int j = 0; j < 4; j++)
                bfr[j] = *(const bf16x8*)(Br + (wn * 64 + j * 16 + lr) * 128 + colb);
#pragma unroll
            for (int i = 0; i < 4; i++)
#pragma unroll
                for (int j = 0; j < 4; j++)
                    acc[i][j] = __builtin_amdgcn_mfma_f32_16x16x32_bf16(af[i], bfr[j], acc[i][j], 0, 0, 0);
        }
        __builtin_amdgcn_sched_barrier(0);
        __builtin_amdgcn_s_barrier();
        cur ^= 1;
    }

    const int rq = lane >> 4;
#pragma unroll
    for (int j = 0; j < 4; j++) {
        int col = bn + wn * 64 + j * 16 + lr;
        float bv = bias[col];
#pragma unroll
        for (int i = 0; i < 4; i++) {
            int rowb = bm + wm * 64 + i * 16 + rq * 4;
            float o[4];
#pragma unroll
            for (int r = 0; r < 4; r++) {
                float t = acc[i][j][r] + bv;
                if (ADD_RES) t += bf2f(xres[(size_t)(rowb + r) * N + col]);
                if (ACT_GELU) t = gelu_f(t);
                o[r] = t;
            }
            if (VT_FUSE && col >= 2 * DD && col < 3 * DD) {
                int h = (col - 2 * DD) >> 6, d = col & 63;
                int b = rowb >> 12;
                int s0 = rowb & (SS - 1);
                ushort4 ov = { bfb(o[0]), bfb(o[1]), bfb(o[2]), bfb(o[3]) };
                *(ushort4*)&vtv[((size_t)((b * HH + h) * 64 + d)) * SS + s0] = ov;
            } else if (OUT_BF16) {
#pragma unroll
                for (int r = 0; r < 4; r++)
                    ((unsigned short*)Cv)[(size_t)(rowb + r) * N + col] = bfb(o[r]);
            } else {
#pragma unroll
                for (int r = 0; r < 4; r++)
                    ((float*)Cv)[(size_t)(rowb + r) * N + col] = o[r];
            }
        }
    }
}

// ---------------- MFMA sliding-window flash attention (128-q blocks, dbuf pipeline) ----------------
__global__ __launch_bounds__(256) void swin_mfma_k(
        const unsigned short* __restrict__ packed,
        const unsigned short* __restrict__ vt,
        const int* __restrict__ mask,
        unsigned short* __restrict__ O)
{
    __shared__ __align__(16) char smem[52736];
    const int c2 = blockIdx.x, h = blockIdx.y, b = blockIdx.z;
    const int tid = threadIdx.x;
    const int lane = tid & 63, wv = tid >> 6;
    const int l15 = lane & 15, g = lane >> 4;
    const int bh = b * HH + h;
    const int q0 = c2 * 128;

    char* PB = smem + 32768 + wv * 4096;
    float* maskAll = (float*)(smem + 49152);
    float* sA = (float*)(smem + 51712);
    float* sB = (float*)(smem + 52224);

    const char* pk_bytes = (const char*)packed;
    const char* vt_bytes = (const char*)vt;

    bf16x8 qf[2][2];
#pragma unroll
    for (int j = 0; j < 2; j++)
#pragma unroll
        for (int kk = 0; kk < 2; kk++)
            qf[j][kk] = *(const bf16x8*)(packed +
                (size_t)(b * SS + q0 + wv * 32 + j * 16 + l15) * 3840 + h * 64 + kk * 32 + g * 8);
    bf16x8 gkf[2];
#pragma unroll
    for (int kk = 0; kk < 2; kk++)
        gkf[kk] = *(const bf16x8*)(packed + (size_t)(b * SS) * 3840 + DD + h * 64 + kk * 32 + g * 8);
    float v0r[4];
#pragma unroll
    for (int jd = 0; jd < 4; jd++)
        v0r[jd] = bf2f(vt[(size_t)(bh * 64 + jd * 16 + l15) * SS]);

    f32x4 o_[2][4];
#pragma unroll
    for (int i = 0; i < 2; i++)
#pragma unroll
        for (int j = 0; j < 4; j++) o_[i][j] = (f32x4){0.f, 0.f, 0.f, 0.f};
    float m_[2] = { -1e20f, -1e20f };
    float l_[2] = { 0.f, 0.f };

    const int rswz = (l15 & 7) << 4;
    const int kt_s = max(0, 4 - 2 * c2);
    const int kt_e = min(10, 68 - 2 * c2);
    const int lo = wv >> 1;

    auto stage = [&](int ib, int kt) {
        const int kpos0 = q0 - 256 + kt * 64;
        char* KTd = smem + ib * 8192;
        char* VTd = smem + 16384 + ib * 8192;
        int off = tid * 16;
#pragma unroll
        for (int ch = 0; ch < 2; ch++) {
            int o2 = off + ch * 4096;
            int row = o2 >> 7, bc = o2 & 127;
            int srcc = bc ^ ((row & 7) << 4);
            gload16(pk_bytes + (size_t)(b * SS + kpos0 + row) * 7680 + 1536 + h * 128 + srcc,
                    KTd + o2);
            gload16(vt_bytes + (size_t)(bh * 64 + row) * 8192 + (size_t)(kpos0 * 2 + srcc),
                    VTd + o2);
        }
    };

    stage(0, kt_s);
    {
        int span = (kt_e - kt_s) * 64;
        int base_k = q0 - 256 + kt_s * 64;
        for (int idx = tid; idx < span; idx += 256) {
            int kp = base_k + idx;
            maskAll[kt_s * 64 + idx] = (mask[b * SS + kp] > 0) ? 0.f : -1e30f;
        }
    }
    __syncthreads();

    int cur = 0;
    for (int kt = kt_s; kt < kt_e; kt++) {
        if (kt + 1 < kt_e) stage(cur ^ 1, kt + 1);

        const int dl = kt - lo;
        if (dl >= 0 && dl <= 8) {
            const char* KT = smem + cur * 8192;
            const char* VT = smem + 16384 + cur * 8192;
            const bool edge = (dl == 0) || (dl == 8);

            f32x4 mrd[4];
#pragma unroll
            for (int i = 0; i < 4; i++)
                mrd[i] = *(const f32x4*)&maskAll[kt * 64 + i * 16 + g * 4];

            f32x4 s_[4][2];
#pragma unroll
            for (int i = 0; i < 4; i++)
#pragma unroll
                for (int j = 0; j < 2; j++) s_[i][j] = (f32x4){0.f, 0.f, 0.f, 0.f};
            __builtin_amdgcn_s_setprio(1);
#pragma unroll
            for (int kk = 0; kk < 2; kk++) {
                bf16x8 af[4];
#pragma unroll
                for (int i = 0; i < 4; i++)
                    af[i] = *(const bf16x8*)(KT + (i * 16 + l15) * 128 + ((kk * 64 + g * 16) ^ rswz));
#pragma unroll
                for (int i = 0; i < 4; i++)
#pragma unroll
                    for (int j = 0; j < 2; j++)
                        s_[i][j] = __builtin_amdgcn_mfma_f32_16x16x32_bf16(af[i], qf[j][kk], s_[i][j], 0, 0, 0);
            }
            __builtin_amdgcn_s_setprio(0);

#pragma unroll
            for (int j = 0; j < 2; j++) {
                float tm = -1e30f;
                if (edge) {
#pragma unroll
                    for (int i = 0; i < 4; i++) {
#pragma unroll
                        for (int r = 0; r < 4; r++) {
                            float v = fmaf(s_[i][j][r], 0.125f, mrd[i][r]);
                            int rel = kt * 64 - 256 + i * 16 + g * 4 + r - wv * 32 - j * 16 - l15;
                            v = (rel > 256 || rel < -256) ? -1e30f : v;
                            s_[i][j][r] = v;
                            tm = fmaxf(tm, v);
                        }
                    }
                } else {
#pragma unroll
                    for (int i = 0; i < 4; i++) {
#pragma unroll
                        for (int r = 0; r < 4; r++) {
                            float v = fmaf(s_[i][j][r], 0.125f, mrd[i][r]);
                            s_[i][j][r] = v;
                            tm = fmaxf(tm, v);
                        }
                    }
                }
                tm = fmaxf(tm, __shfl_xor(tm, 16));
                tm = fmaxf(tm, __shfl_xor(tm, 32));
                float mn = fmaxf(m_[j], tm);
                float fac = __expf(m_[j] - mn);
                m_[j] = mn;
                float ls = 0.f;
                int q32 = j * 16 + l15;
#pragma unroll
                for (int i = 0; i < 4; i++) {
                    float p0 = __expf(s_[i][j][0] - mn);
                    float p1 = __expf(s_[i][j][1] - mn);
                    float p2 = __expf(s_[i][j][2] - mn);
                    float p3 = __expf(s_[i][j][3] - mn);
                    ls += (p0 + p1) + (p2 + p3);
                    uint2 pw;
                    pw.x = (unsigned int)bfb(p0) | ((unsigned int)bfb(p1) << 16);
                    pw.y = (unsigned int)bfb(p2) | ((unsigned int)bfb(p3) << 16);
                    *(uint2*)(PB + q32 * 128 + ((i * 32 + g * 8) ^ rswz)) = pw;
                }
                ls += __shfl_xor(ls, 16);
                ls += __shfl_xor(ls, 32);
                l_[j] = l_[j] * fac + ls;
                if (g == 0) sA[wv * 32 + q32] = fac;
            }

#pragma unroll
            for (int iq = 0; iq < 2; iq++) {
                f32x4 fc = *(const f32x4*)&sA[wv * 32 + iq * 16 + g * 4];
#pragma unroll
                for (int jd = 0; jd < 4; jd++)
#pragma unroll
                    for (int r = 0; r < 4; r++) o_[iq][jd][r] *= fc[r];
            }
            __builtin_amdgcn_s_setprio(1);
#pragma unroll
            for (int kk = 0; kk < 2; kk++) {
                bf16x8 pa[2], vb[4];
#pragma unroll
                for (int iq = 0; iq < 2; iq++)
                    pa[iq] = *(const bf16x8*)(PB + (iq * 16 + l15) * 128 + ((kk * 64 + g * 16) ^ rswz));
#pragma unroll
                for (int jd = 0; jd < 4; jd++)
                    vb[jd] = *(const bf16x8*)(VT + (jd * 16 + l15) * 128 + ((kk * 64 + g * 16) ^ rswz));
#pragma unroll
                for (int iq = 0; iq < 2; iq++)
#pragma unroll
                    for (int jd = 0; jd < 4; jd++)
                        o_[iq][jd] = __builtin_amdgcn_mfma_f32_16x16x32_bf16(pa[iq], vb[jd], o_[iq][jd], 0, 0, 0);
            }
            __builtin_amdgcn_s_setprio(0);
        }

        asm volatile("s_waitcnt vmcnt(0)" ::: "memory");
        __builtin_amdgcn_sched_barrier(0);
        __builtin_amdgcn_s_barrier();
        __builtin_amdgcn_sched_barrier(0);
        cur ^= 1;
    }

#pragma unroll
    for (int j = 0; j < 2; j++) {
        float pd = 0.f;
#pragma unroll
        for (int kk = 0; kk < 2; kk++)
#pragma unroll
            for (int e = 0; e < 8; e++)
                pd += bf2f((unsigned short)qf[j][kk][e]) * bf2f((unsigned short)gkf[kk][e]);
        pd += __shfl_xor(pd, 16);
        pd += __shfl_xor(pd, 32);
        float sg = pd * 0.125f;
        float mf = fmaxf(m_[j], sg);
        float fac = __expf(m_[j] - mf);
        float pg = __expf(sg - mf);
        float lf = l_[j] * fac + pg;
        float inv = 1.f / lf;
        if (g == 0) {
            sA[wv * 32 + j * 16 + l15] = fac * inv;
            sB[wv * 32 + j * 16 + l15] = pg * inv;
        }
    }
#pragma unroll
    for (int iq = 0; iq < 2; iq++) {
        f32x4 fA = *(const f32x4*)&sA[wv * 32 + iq * 16 + g * 4];
        f32x4 fB = *(const f32x4*)&sB[wv * 32 + iq * 16 + g * 4];
#pragma unroll
        for (int jd = 0; jd < 4; jd++) {
#pragma unroll
            for (int r = 0; r < 4; r++) {
                float val = o_[iq][jd][r] * fA[r] + fB[r] * v0r[jd];
                int row = b * SS + q0 + wv * 32 + iq * 16 + g * 4 + r;
                O[(size_t)row * DD + h * 64 + jd * 16 + l15] = bfb(val);
            }
        }
    }
}

// ---------------- global-token attention, phase 1 ----------------
__global__ __launch_bounds__(256) void gattn1_k(const float* __restrict__ qg,
        const unsigned short* __restrict__ packed, const int* __restrict__ mask,
        float* __restrict__ pm, float* __restrict__ pl, float* __restrict__ po)
{
    int cc = blockIdx.x, h = blockIdx.y, b = blockIdx.z;
    int tid = threadIdx.x;
    __shared__ float qs[64], red[256], ps[256], ored[4][64];
    if (tid < 64) qs[tid] = qg[b * DD + h * 64 + tid];
    __syncthreads();
    int s = cc * 256 + tid;
    const unsigned short* kr = packed + (size_t)(b * SS + s) * 3840 + 3 * DD + h * 64;
    float a = 0.f;
#pragma unroll
    for (int d8 = 0; d8 < 8; d8++) {
        bf16x8 kv = *(const bf16x8*)(kr + d8 * 8);
#pragma unroll
        for (int e = 0; e < 8; e++)
            a = fmaf(qs[d8 * 8 + e], bf2f((unsigned short)kv[e]), a);
    }
    a *= 0.125f;
    float sv = (mask[b * SS + s] > 0) ? a : -1e9f;
    red[tid] = sv; __syncthreads();
    for (int o = 128; o > 0; o >>= 1) {
        if (tid < o) red[tid] = fmaxf(red[tid], red[tid + o]);
        __syncthreads();
    }
    float mx = red[0]; __syncthreads();
    float p = __expf(sv - mx);
    ps[tid] = p;
    red[tid] = p; __syncthreads();
    for (int o = 128; o > 0; o >>= 1) {
        if (tid < o) red[tid] += red[tid + o];
        __syncthreads();
    }
    float ls = red[0];
    int d = tid & 63, grp = tid >> 6;
    const unsigned short* vgb = packed + 4 * DD + h * 64 + d;
    float oa = 0.f;
    for (int t = 0; t < 64; t++) {
        int srow = cc * 256 + grp * 64 + t;
        oa = fmaf(ps[grp * 64 + t], bf2f(vgb[(size_t)(b * SS + srow) * 3840]), oa);
    }
    ored[grp][d] = oa; __syncthreads();
    if (tid < 64) {
        int idx = (b * HH + h) * 16 + cc;
        po[(size_t)idx * 64 + tid] = ored[0][tid] + ored[1][tid] + ored[2][tid] + ored[3][tid];
        if (tid == 0) { pm[idx] = mx; pl[idx] = ls; }
    }
}

// ---------------- global-token attention, phase 2 ----------------
__global__ __launch_bounds__(64) void gattn2_k(const float* __restrict__ pm,
        const float* __restrict__ pl, const float* __restrict__ po,
        unsigned short* __restrict__ O)
{
    int h = blockIdx.x, b = blockIdx.y;
    int tid = threadIdx.x;
    int base = (b * HH + h) * 16;
    float mx = -1e30f;
    for (int c2 = 0; c2 < 16; c2++) mx = fmaxf(mx, pm[base + c2]);
    float den = 0.f, oa = 0.f;
    for (int c2 = 0; c2 < 16; c2++) {
        float w = __expf(pm[base + c2] - mx);
        den = fmaf(pl[base + c2], w, den);
        oa = fmaf(po[(size_t)(base + c2) * 64 + tid], w, oa);
    }
    O[(size_t)(b * SS) * DD + h * 64 + tid] = bfb(oa / den);
}

// ---------------- row-GEMV (bf16 activations) ----------------
template<int ACT_TANH>
__global__ __launch_bounds__(256) void rowgemv_k(const unsigned short* __restrict__ x,
        size_t xstride, const float* __restrict__ W, const float* __restrict__ bias,
        float* __restrict__ dst, int N)
{
    int b = blockIdx.y;
    int colL = threadIdx.x & 63, part = threadIdx.x >> 6;
    int col = blockIdx.x * 64 + colL;
    __shared__ float partial[4][64];
    const unsigned short* xr = x + (size_t)b * xstride;
    float a = 0.f;
    for (int k = part * (DD / 4); k < (part + 1) * (DD / 4); k++)
        a = fmaf(bf2f(xr[k]), W[(size_t)k * N + col], a);
    partial[part][colL] = a; __syncthreads();
    if (part == 0) {
        float s = partial[0][colL] + partial[1][colL] + partial[2][colL] + partial[3][colL]
                + bias[col];
        if (ACT_TANH) s = tanhf(s);
        dst[b * N + col] = s;
    }
}

// ---------------- classifier ----------------
__global__ __launch_bounds__(256) void cls_k(const float* __restrict__ pooled,
        const float* __restrict__ Wc, const float* __restrict__ bc,
        float* __restrict__ out)
{
    int lane = threadIdx.x & 63, pair = threadIdx.x >> 6;
    int b = pair >> 1, cls = pair & 1;
    float a = 0.f;
#pragma unroll
    for (int j = 0; j < 12; j++) {
        int k = lane + j * 64;
        a = fmaf(pooled[b * DD + k], Wc[k * 2 + cls], a);
    }
#pragma unroll
    for (int o = 1; o < 64; o <<= 1) a += __shfl_xor(a, o);
    if (lane == 0) out[b * 2 + cls] = a + bc[cls];
}

extern "C" void kernel_launch(void* const* d_in, const int* in_sizes, int n_in,
                              void* d_out, int out_size, void* d_ws, size_t ws_size,
                              hipStream_t stream) {
    const int*   input_ids = (const int*)d_in[0];
    const int*   amask     = (const int*)d_in[1];
    const float* word_emb  = (const float*)d_in[2];
    const float* pos_emb   = (const float*)d_in[3];
    const float* ln_e_g    = (const float*)d_in[4];
    const float* ln_e_b    = (const float*)d_in[5];
    const float* Wq  = (const float*)d_in[6];  const float* bq  = (const float*)d_in[7];
    const float* Wk  = (const float*)d_in[8];  const float* bk  = (const float*)d_in[9];
    const float* Wv  = (const float*)d_in[10]; const float* bv  = (const float*)d_in[11];
    const float* Wqg = (const float*)d_in[12]; const float* bqg = (const float*)d_in[13];
    const float* Wkg = (const float*)d_in[14]; const float* bkg = (const float*)d_in[15];
    const float* Wvg = (const float*)d_in[16]; const float* bvg = (const float*)d_in[17];
    const float* Wo  = (const float*)d_in[18]; const float* bo  = (const float*)d_in[19];
    const float* ln1_g = (const float*)d_in[20]; const float* ln1_b = (const float*)d_in[21];
    const float* W1  = (const float*)d_in[22]; const float* bf1 = (const float*)d_in[23];
    const float* W2  = (const float*)d_in[24]; const float* bf2 = (const float*)d_in[25];
    const float* ln2_g = (const float*)d_in[26]; const float* ln2_b = (const float*)d_in[27];
    const float* Wp  = (const float*)d_in[28]; const float* bp  = (const float*)d_in[29];
    const float* Wc  = (const float*)d_in[30]; const float* bc  = (const float*)d_in[31];
    float* out = (float*)d_out;

    char* wsb = (char*)d_ws;
    unsigned short* xbf    = (unsigned short*)(wsb + 25165824);
    unsigned short* packed = (unsigned short*)(wsb + 37748736);
    unsigned short* vtb    = (unsigned short*)(wsb + 100663296);
    unsigned short* aout   = (unsigned short*)(wsb + 113246208);
    unsigned short* hf     = (unsigned short*)(wsb + 125829120);   // bf16 pre-LN buffer
    char*           wts    = wsb + 150994944;
    float*          b5     = (float*)(wsb + 184025088);
    float*          qg     = (float*)(wsb + 184055808);
    float*          pm     = (float*)(wsb + 184061952);
    float*          pl     = (float*)(wsb + 184063488);
    float*          po     = (float*)(wsb + 184065024);
    float*          pooled = (float*)(wsb + 184163328);
    unsigned short* mid    = packed;

    const size_t SQ = (size_t)DD * DD;
    const size_t PER_L = (6 * SQ + 2 * (size_t)DD * FF) * 2;
    unsigned short* Wt5[2], *Wo_t[2], *W1_t[2], *W2_t[2];
    for (int l = 0; l < 2; l++) {
        char* base = wts + (size_t)l * PER_L;
        Wt5[l]  = (unsigned short*)base;
        Wo_t[l] = (unsigned short*)(base + 5 * SQ * 2);
        W1_t[l] = (unsigned short*)(base + 6 * SQ * 2);
        W2_t[l] = (unsigned short*)(base + 6 * SQ * 2 + (size_t)DD * FF * 2);
    }

    const int M = BB * SS;

    TP12 t12;
    for (int l = 0; l < 2; l++) {
        t12.s[l * 6 + 0] = Wq  + (size_t)l * SQ;  t12.d[l * 6 + 0] = Wt5[l] + 0 * SQ;
        t12.s[l * 6 + 1] = Wk  + (size_t)l * SQ;  t12.d[l * 6 + 1] = Wt5[l] + 1 * SQ;
        t12.s[l * 6 + 2] = Wv  + (size_t)l * SQ;  t12.d[l * 6 + 2] = Wt5[l] + 2 * SQ;
        t12.s[l * 6 + 3] = Wkg + (size_t)l * SQ;  t12.d[l * 6 + 3] = Wt5[l] + 3 * SQ;
        t12.s[l * 6 + 4] = Wvg + (size_t)l * SQ;  t12.d[l * 6 + 4] = Wt5[l] + 4 * SQ;
        t12.s[l * 6 + 5] = Wo  + (size_t)l * SQ;  t12.d[l * 6 + 5] = Wo_t[l];
    }
    TP4 t4;
    t4.s[0] = W1;                      t4.d[0] = W1_t[0];
    t4.s[1] = W1 + (size_t)DD * FF;    t4.d[1] = W1_t[1];
    t4.s[2] = W2;                      t4.d[2] = W2_t[0];
    t4.s[3] = W2 + (size_t)FF * DD;    t4.d[3] = W2_t[1];

    transpose12_k<<<dim3(24, 24, 12), 256, 0, stream>>>(t12);
    transposeR4_k<<<dim3(96, 24, 4), 256, 0, stream>>>(t4);
    pack_bias5_k<<<(2 * 5 * DD + 255) / 256, 256, 0, stream>>>(bq, bk, bv, bkg, bvg, b5);

    embed_ln_k<<<M, 256, 0, stream>>>(input_ids, word_emb, pos_emb, ln_e_g, ln_e_b, xbf);

    dim3 gqkv(M / 128, 3840 / 128);               // (64, 30)
    dim3 g768(M / 128, DD / 128);                 // (64, 6)
    dim3 g3072(M / 128, FF / 128);                // (64, 24)

    for (int l = 0; l < 2; l++) {
        const float* Wqg_l = Wqg + (size_t)l * SQ; const float* bqg_l = bqg + (size_t)l * DD;
        const float* bo_l  = bo  + (size_t)l * DD;
        const float* bf1_l = bf1 + (size_t)l * FF;
        const float* bf2_l = bf2 + (size_t)l * DD;
        const float* g1_l  = ln1_g + (size_t)l * DD; const float* b1_l = ln1_b + (size_t)l * DD;
        const float* g2_l  = ln2_g + (size_t)l * DD; const float* b2_l = ln2_b + (size_t)l * DD;

        // QKV GEMM with fused V head-transpose (V cols -> vtb; no vtrans kernel)
        mfma_gemm_k<1, 0, 0, 1><<<gqkv, 256, 0, stream>>>(xbf, Wt5[l], b5 + (size_t)l * 3840,
                                                          nullptr, vtb, packed, M, 3840, DD);
        rowgemv_k<0><<<dim3(DD / 64, BB), 256, 0, stream>>>(xbf, (size_t)SS * DD, Wqg_l, bqg_l, qg, DD);

        swin_mfma_k<<<dim3(SS / 128, HH, BB), 256, 0, stream>>>(packed, vtb, amask, aout);
        gattn1_k<<<dim3(16, HH, BB), 256, 0, stream>>>(qg, packed, amask, pm, pl, po);
        gattn2_k<<<dim3(HH, BB), 64, 0, stream>>>(pm, pl, po, aout);

        // h + x(bf16 residual) fused into epilogue; bf16 hf; ln_k normalizes
        mfma_gemm_k<1, 0, 1, 0><<<g768, 256, 0, stream>>>(aout, Wo_t[l], bo_l, xbf, nullptr, hf, M, DD, DD);
        ln_k<<<M, 256, 0, stream>>>(hf, g1_l, b1_l, xbf);

        mfma_gemm_k<1, 1, 0, 0><<<g3072, 256, 0, stream>>>(xbf, W1_t[l], bf1_l, nullptr, nullptr, mid, M, FF, DD);
        mfma_gemm_k<1, 0, 1, 0><<<g768, 256, 0, stream>>>(mid, W2_t[l], bf2_l, xbf, nullptr, hf, M, DD, FF);
        ln_k<<<M, 256, 0, stream>>>(hf, g2_l, b2_l, xbf);
    }

    rowgemv_k<1><<<dim3(DD / 64, BB), 256, 0, stream>>>(xbf, (size_t)SS * DD, Wp, bp, pooled, DD);
    cls_k<<<1, 256, 0, stream>>>(pooled, Wc, bc, out);
}

// Round 18
// 644.683 us; speedup vs baseline: 1.0122x; 1.0122x over previous
//
#include <hip/hip_runtime.h>
#include <hip/hip_bf16.h>
#include <math.h>

#define BB 2
#define SS 4096
#define DD 768
#define HH 12
#define DHH 64
#define WW 256
#define CC 16
#define FF 3072

typedef __attribute__((ext_vector_type(8))) short bf16x8;
typedef __attribute__((ext_vector_type(4))) float f32x4;

struct TP12 { const float* s[12]; unsigned short* d[12]; };
struct TP4  { const float* s[4];  unsigned short* d[4];  };

// gelu(x) = 0.5x(1+tanh(u)) = x * sigmoid(2u), u = 0.79788456(x + 0.044715 x^3)
__device__ __forceinline__ float gelu_f(float x) {
    float u = 0.7978845608028654f * fmaf(0.044715f * x * x, x, x);
    return x / (1.f + __expf(-2.f * u));
}

__device__ __forceinline__ unsigned short bfb(float f) {
    __hip_bfloat16 h = __float2bfloat16(f);
    return *(unsigned short*)&h;
}

__device__ __forceinline__ float bf2f(unsigned short u) {
    return __uint_as_float(((unsigned int)u) << 16);
}

__device__ __forceinline__ void gload16(const void* g, void* l) {
    __builtin_amdgcn_global_load_lds(
        (const __attribute__((address_space(1))) unsigned int*)g,
        (__attribute__((address_space(3))) unsigned int*)l, 16, 0, 0);
}

// ---------------- fused weight transposes: fp32 [K][N] -> bf16 [N][K] ----------------
__global__ __launch_bounds__(256) void transpose12_k(TP12 p)
{
    __shared__ float t[32][33];
    int z = blockIdx.z;
    const float* Wsrc = p.s[z];
    unsigned short* Wt = p.d[z];
    const int K = DD, N = DD;
    int n0 = blockIdx.x * 32, k0 = blockIdx.y * 32;
    int tx = threadIdx.x & 31, ty = threadIdx.x >> 5;
#pragma unroll
    for (int i = 0; i < 32; i += 8)
        t[ty + i][tx] = Wsrc[(size_t)(k0 + ty + i) * N + n0 + tx];
    __syncthreads();
#pragma unroll
    for (int i = 0; i < 32; i += 8)
        Wt[(size_t)(n0 + ty + i) * K + k0 + tx] = bfb(t[tx][ty + i]);
}

__global__ __launch_bounds__(256) void transposeR4_k(TP4 p)
{
    __shared__ float t[32][33];
    int z = blockIdx.z;
    const float* Wsrc = p.s[z];
    unsigned short* Wt = p.d[z];
    int K, N, n0, k0;
    if (z < 2) { K = DD; N = FF; n0 = blockIdx.x * 32; k0 = blockIdx.y * 32; }
    else { K = FF; N = DD; int cell = blockIdx.y * 96 + blockIdx.x;
           n0 = (cell % 24) * 32; k0 = (cell / 24) * 32; }
    int tx = threadIdx.x & 31, ty = threadIdx.x >> 5;
#pragma unroll
    for (int i = 0; i < 32; i += 8)
        t[ty + i][tx] = Wsrc[(size_t)(k0 + ty + i) * N + n0 + tx];
    __syncthreads();
#pragma unroll
    for (int i = 0; i < 32; i += 8)
        Wt[(size_t)(n0 + ty + i) * K + k0 + tx] = bfb(t[tx][ty + i]);
}

// ---------------- pack 5 bias vectors [2][768] each -> [2][3840] ----------------
__global__ __launch_bounds__(256) void pack_bias5_k(const float* __restrict__ b0,
        const float* __restrict__ b1, const float* __restrict__ b2,
        const float* __restrict__ b3, const float* __restrict__ b4,
        float* __restrict__ dst)
{
    int gid = blockIdx.x * 256 + threadIdx.x;
    if (gid >= 2 * 5 * DD) return;
    int l = gid / (5 * DD), r = gid % (5 * DD), seg = r / DD, i = r % DD;
    const float* srcs[5] = { b0, b1, b2, b3, b4 };
    dst[gid] = srcs[seg][l * DD + i];
}

// ---------------- embedding + LayerNorm (bf16 activation stream only) ----------------
__global__ __launch_bounds__(256) void embed_ln_k(const int* __restrict__ ids,
        const float* __restrict__ wemb, const float* __restrict__ pemb,
        const float* __restrict__ g, const float* __restrict__ bta,
        unsigned short* __restrict__ xbf)
{
    int row = blockIdx.x;
    int s = row & (SS - 1);
    int tid = threadIdx.x;
    int lane = tid & 63, wvi = tid >> 6;
    __shared__ float red[8];
    float4 v = { 0.f, 0.f, 0.f, 0.f };
    if (tid < 192) {
        const float4* we = (const float4*)(wemb + (size_t)ids[row] * DD);
        const float4* pe = (const float4*)(pemb + (size_t)s * DD);
        float4 a = we[tid], b = pe[tid];
        v.x = a.x + b.x; v.y = a.y + b.y; v.z = a.z + b.z; v.w = a.w + b.w;
    }
    float sum = (v.x + v.y) + (v.z + v.w);
    float sq = fmaf(v.x, v.x, fmaf(v.y, v.y, fmaf(v.z, v.z, v.w * v.w)));
#pragma unroll
    for (int o = 1; o < 64; o <<= 1) {
        sum += __shfl_xor(sum, o);
        sq  += __shfl_xor(sq, o);
    }
    if (lane == 0) { red[wvi] = sum; red[4 + wvi] = sq; }
    __syncthreads();
    float S = (red[0] + red[1]) + (red[2] + red[3]);
    float Q = (red[4] + red[5]) + (red[6] + red[7]);
    float mean = S * (1.f / DD);
    float var = Q * (1.f / DD) - mean * mean;
    float rstd = rsqrtf(var + 1e-5f);
    if (tid < 192) {
        float4 gg = ((const float4*)g)[tid];
        float4 bb = ((const float4*)bta)[tid];
        float4 o;
        o.x = (v.x - mean) * rstd * gg.x + bb.x;
        o.y = (v.y - mean) * rstd * gg.y + bb.y;
        o.z = (v.z - mean) * rstd * gg.z + bb.z;
        o.w = (v.w - mean) * rstd * gg.w + bb.w;
        ushort4 ob = { bfb(o.x), bfb(o.y), bfb(o.z), bfb(o.w) };
        ((ushort4*)(xbf + (size_t)row * DD))[tid] = ob;
    }
}

// ---------------- single-input LayerNorm (residual pre-added in GEMM epilogue) ----------------
__global__ __launch_bounds__(256) void ln_k(const float* __restrict__ hin,
        const float* __restrict__ g, const float* __restrict__ bta,
        unsigned short* __restrict__ xbf)
{
    int row = blockIdx.x;
    int tid = threadIdx.x;
    int lane = tid & 63, wvi = tid >> 6;
    __shared__ float red[8];
    float4 v = { 0.f, 0.f, 0.f, 0.f };
    if (tid < 192)
        v = ((const float4*)(hin + (size_t)row * DD))[tid];
    float sum = (v.x + v.y) + (v.z + v.w);
    float sq = fmaf(v.x, v.x, fmaf(v.y, v.y, fmaf(v.z, v.z, v.w * v.w)));
#pragma unroll
    for (int o = 1; o < 64; o <<= 1) {
        sum += __shfl_xor(sum, o);
        sq  += __shfl_xor(sq, o);
    }
    if (lane == 0) { red[wvi] = sum; red[4 + wvi] = sq; }
    __syncthreads();
    float S = (red[0] + red[1]) + (red[2] + red[3]);
    float Q = (red[4] + red[5]) + (red[6] + red[7]);
    float mean = S * (1.f / DD);
    float var = Q * (1.f / DD) - mean * mean;
    float rstd = rsqrtf(var + 1e-5f);
    if (tid < 192) {
        float4 gg = ((const float4*)g)[tid];
        float4 bb = ((const float4*)bta)[tid];
        float4 o;
        o.x = (v.x - mean) * rstd * gg.x + bb.x;
        o.y = (v.y - mean) * rstd * gg.y + bb.y;
        o.z = (v.z - mean) * rstd * gg.z + bb.z;
        o.w = (v.w - mean) * rstd * gg.w + bb.w;
        ushort4 ob = { bfb(o.x), bfb(o.y), bfb(o.z), bfb(o.w) };
        ((ushort4*)(xbf + (size_t)row * DD))[tid] = ob;
    }
}

// ---------------- 128-tile bf16 MFMA GEMM, BK=64, XOR-swizzled LDS, bn-fast L2 tiling,
// dbuf + counted-vmcnt pipeline; optional fused bf16-residual add; optional fused
// V head-transpose (VT_FUSE: cols [1536,2304) write vt[(b*H+h)*64+d][s] as ushort4). ----------------
template<int OUT_BF16, int ACT_GELU, int ADD_RES, int VT_FUSE>
__global__ __launch_bounds__(256) void mfma_gemm_k(
        const unsigned short* __restrict__ A,
        const unsigned short* __restrict__ Bt,
        const float* __restrict__ bias,
        const unsigned short* __restrict__ xres,
        unsigned short* __restrict__ vtv,
        void* __restrict__ Cv, int M, int N, int K)
{
    __shared__ short As[2 * 128 * 64];
    __shared__ short Bs[2 * 128 * 64];
    const int tid = threadIdx.x;
    const int lane = tid & 63, wv = tid >> 6;
    int nbx = gridDim.x;
    int nby = gridDim.y;
    int nwg = nbx * nby;
    int lid = blockIdx.y * nbx + blockIdx.x;
    int nid = ((nwg & 7) == 0) ? ((lid & 7) * (nwg >> 3) + (lid >> 3)) : lid;
    const int bm = (nid / nby) * 128, bn = (nid % nby) * 128;
    const int wm = wv >> 1, wn = wv & 1;

    const int srow0 = (tid * 16) >> 7;
    const int sbc   = (tid * 16) & 127;
    const int srcc  = sbc ^ ((srow0 & 7) << 4);
    const int ldst  = tid * 16;
    const char* Ab = (const char*)(A + (size_t)bm * K);
    const char* Bb = (const char*)(Bt + (size_t)bn * K);

    f32x4 acc[4][4];
#pragma unroll
    for (int i = 0; i < 4; i++)
#pragma unroll
        for (int j = 0; j < 4; j++) acc[i][j] = (f32x4){0.f, 0.f, 0.f, 0.f};

    const int lr = lane & 15;
    const int g = lane >> 4;
    const int rswz = (lr & 7) << 4;
    const int NK = K >> 6;

    auto stage = [&](int ib, int t) {
        const int k0 = t << 6;
        char* Ad = (char*)As + ib * 16384;
        char* Bd = (char*)Bs + ib * 16384;
#pragma unroll
        for (int p = 0; p < 4; p++) {
            size_t roff = (size_t)(srow0 + p * 32) * (K * 2) + (size_t)k0 * 2 + srcc;
            gload16(Ab + roff, Ad + p * 4096 + ldst);
            gload16(Bb + roff, Bd + p * 4096 + ldst);
        }
    };

    stage(0, 0);

    int cur = 0;
    for (int t = 0; t < NK; t++) {
        if (t + 1 < NK) {
            stage(cur ^ 1, t + 1);
            asm volatile("s_waitcnt vmcnt(8)" ::: "memory");
        } else {
            asm volatile("s_waitcnt vmcnt(0)" ::: "memory");
        }
        __builtin_amdgcn_sched_barrier(0);
        __builtin_amdgcn_s_barrier();
        __builtin_amdgcn_sched_barrier(0);

        const char* Ar = (const char*)As + cur * 16384;
        const char* Br = (const char*)Bs + cur * 16384;
#pragma unroll
        for (int kk = 0; kk < 2; kk++) {
            int colb = (kk * 64 + g * 16) ^ rswz;
            bf16x8 af[4], bfr[4];
#pragma unroll
            for (int i = 0; i < 4; i++)
                af[i] = *(const bf16x8*)(Ar + (wm * 64 + i * 16 + lr) * 128 + colb);
#pragma unroll
            for (int j = 0; j < 4; j++)
                bfr[j] = *(const bf16x8*)(Br + (wn * 64 + j * 16 + lr) * 128 + colb);
#pragma unroll
            for (int i = 0; i < 4; i++)
#pragma unroll
                for (int j = 0; j < 4; j++)
                    acc[i][j] = __builtin_amdgcn_mfma_f32_16x16x32_bf16(af[i], bfr[j], acc[i][j], 0, 0, 0);
        }
        __builtin_amdgcn_sched_barrier(0);
        __builtin_amdgcn_s_barrier();
        cur ^= 1;
    }

    const int rq = lane >> 4;
#pragma unroll
    for (int j = 0; j < 4; j++) {
        int col = bn + wn * 64 + j * 16 + lr;
        float bv = bias[col];
#pragma unroll
        for (int i = 0; i < 4; i++) {
            int rowb = bm + wm * 64 + i * 16 + rq * 4;
            float o[4];
#pragma unroll
            for (int r = 0; r < 4; r++) {
                float t = acc[i][j][r] + bv;
                if (ADD_RES) t += bf2f(xres[(size_t)(rowb + r) * N + col]);
                if (ACT_GELU) t = gelu_f(t);
                o[r] = t;
            }
            if (VT_FUSE && col >= 2 * DD && col < 3 * DD) {
                int h = (col - 2 * DD) >> 6, d = col & 63;
                int b = rowb >> 12;
                int s0 = rowb & (SS - 1);
                ushort4 ov = { bfb(o[0]), bfb(o[1]), bfb(o[2]), bfb(o[3]) };
                *(ushort4*)&vtv[((size_t)((b * HH + h) * 64 + d)) * SS + s0] = ov;
            } else if (OUT_BF16) {
#pragma unroll
                for (int r = 0; r < 4; r++)
                    ((unsigned short*)Cv)[(size_t)(rowb + r) * N + col] = bfb(o[r]);
            } else {
#pragma unroll
                for (int r = 0; r < 4; r++)
                    ((float*)Cv)[(size_t)(rowb + r) * N + col] = o[r];
            }
        }
    }
}

// ---------------- MFMA sliding-window flash attention (128-q blocks, dbuf pipeline) ----------------
__global__ __launch_bounds__(256) void swin_mfma_k(
        const unsigned short* __restrict__ packed,
        const unsigned short* __restrict__ vt,
        const int* __restrict__ mask,
        unsigned short* __restrict__ O)
{
    __shared__ __align__(16) char smem[52736];
    const int c2 = blockIdx.x, h = blockIdx.y, b = blockIdx.z;
    const int tid = threadIdx.x;
    const int lane = tid & 63, wv = tid >> 6;
    const int l15 = lane & 15, g = lane >> 4;
    const int bh = b * HH + h;
    const int q0 = c2 * 128;

    char* PB = smem + 32768 + wv * 4096;
    float* maskAll = (float*)(smem + 49152);
    float* sA = (float*)(smem + 51712);
    float* sB = (float*)(smem + 52224);

    const char* pk_bytes = (const char*)packed;
    const char* vt_bytes = (const char*)vt;

    bf16x8 qf[2][2];
#pragma unroll
    for (int j = 0; j < 2; j++)
#pragma unroll
        for (int kk = 0; kk < 2; kk++)
            qf[j][kk] = *(const bf16x8*)(packed +
                (size_t)(b * SS + q0 + wv * 32 + j * 16 + l15) * 3840 + h * 64 + kk * 32 + g * 8);
    bf16x8 gkf[2];
#pragma unroll
    for (int kk = 0; kk < 2; kk++)
        gkf[kk] = *(const bf16x8*)(packed + (size_t)(b * SS) * 3840 + DD + h * 64 + kk * 32 + g * 8);
    float v0r[4];
#pragma unroll
    for (int jd = 0; jd < 4; jd++)
        v0r[jd] = bf2f(vt[(size_t)(bh * 64 + jd * 16 + l15) * SS]);

    f32x4 o_[2][4];
#pragma unroll
    for (int i = 0; i < 2; i++)
#pragma unroll
        for (int j = 0; j < 4; j++) o_[i][j] = (f32x4){0.f, 0.f, 0.f, 0.f};
    float m_[2] = { -1e20f, -1e20f };
    float l_[2] = { 0.f, 0.f };

    const int rswz = (l15 & 7) << 4;
    const int kt_s = max(0, 4 - 2 * c2);
    const int kt_e = min(10, 68 - 2 * c2);
    const int lo = wv >> 1;

    auto stage = [&](int ib, int kt) {
        const int kpos0 = q0 - 256 + kt * 64;
        char* KTd = smem + ib * 8192;
        char* VTd = smem + 16384 + ib * 8192;
        int off = tid * 16;
#pragma unroll
        for (int ch = 0; ch < 2; ch++) {
            int o2 = off + ch * 4096;
            int row = o2 >> 7, bc = o2 & 127;
            int srcc = bc ^ ((row & 7) << 4);
            gload16(pk_bytes + (size_t)(b * SS + kpos0 + row) * 7680 + 1536 + h * 128 + srcc,
                    KTd + o2);
            gload16(vt_bytes + (size_t)(bh * 64 + row) * 8192 + (size_t)(kpos0 * 2 + srcc),
                    VTd + o2);
        }
    };

    stage(0, kt_s);
    {
        int span = (kt_e - kt_s) * 64;
        int base_k = q0 - 256 + kt_s * 64;
        for (int idx = tid; idx < span; idx += 256) {
            int kp = base_k + idx;
            maskAll[kt_s * 64 + idx] = (mask[b * SS + kp] > 0) ? 0.f : -1e30f;
        }
    }
    __syncthreads();

    int cur = 0;
    for (int kt = kt_s; kt < kt_e; kt++) {
        if (kt + 1 < kt_e) stage(cur ^ 1, kt + 1);

        const int dl = kt - lo;
        if (dl >= 0 && dl <= 8) {
            const char* KT = smem + cur * 8192;
            const char* VT = smem + 16384 + cur * 8192;
            const bool edge = (dl == 0) || (dl == 8);

            f32x4 mrd[4];
#pragma unroll
            for (int i = 0; i < 4; i++)
                mrd[i] = *(const f32x4*)&maskAll[kt * 64 + i * 16 + g * 4];

            f32x4 s_[4][2];
#pragma unroll
            for (int i = 0; i < 4; i++)
#pragma unroll
                for (int j = 0; j < 2; j++) s_[i][j] = (f32x4){0.f, 0.f, 0.f, 0.f};
            __builtin_amdgcn_s_setprio(1);
#pragma unroll
            for (int kk = 0; kk < 2; kk++) {
                bf16x8 af[4];
#pragma unroll
                for (int i = 0; i < 4; i++)
                    af[i] = *(const bf16x8*)(KT + (i * 16 + l15) * 128 + ((kk * 64 + g * 16) ^ rswz));
#pragma unroll
                for (int i = 0; i < 4; i++)
#pragma unroll
                    for (int j = 0; j < 2; j++)
                        s_[i][j] = __builtin_amdgcn_mfma_f32_16x16x32_bf16(af[i], qf[j][kk], s_[i][j], 0, 0, 0);
            }
            __builtin_amdgcn_s_setprio(0);

#pragma unroll
            for (int j = 0; j < 2; j++) {
                float tm = -1e30f;
                if (edge) {
#pragma unroll
                    for (int i = 0; i < 4; i++) {
#pragma unroll
                        for (int r = 0; r < 4; r++) {
                            float v = fmaf(s_[i][j][r], 0.125f, mrd[i][r]);
                            int rel = kt * 64 - 256 + i * 16 + g * 4 + r - wv * 32 - j * 16 - l15;
                            v = (rel > 256 || rel < -256) ? -1e30f : v;
                            s_[i][j][r] = v;
                            tm = fmaxf(tm, v);
                        }
                    }
                } else {
#pragma unroll
                    for (int i = 0; i < 4; i++) {
#pragma unroll
                        for (int r = 0; r < 4; r++) {
                            float v = fmaf(s_[i][j][r], 0.125f, mrd[i][r]);
                            s_[i][j][r] = v;
                            tm = fmaxf(tm, v);
                        }
                    }
                }
                tm = fmaxf(tm, __shfl_xor(tm, 16));
                tm = fmaxf(tm, __shfl_xor(tm, 32));
                float mn = fmaxf(m_[j], tm);
                float fac = __expf(m_[j] - mn);
                m_[j] = mn;
                float ls = 0.f;
                int q32 = j * 16 + l15;
#pragma unroll
                for (int i = 0; i < 4; i++) {
                    float p0 = __expf(s_[i][j][0] - mn);
                    float p1 = __expf(s_[i][j][1] - mn);
                    float p2 = __expf(s_[i][j][2] - mn);
                    float p3 = __expf(s_[i][j][3] - mn);
                    ls += (p0 + p1) + (p2 + p3);
                    uint2 pw;
                    pw.x = (unsigned int)bfb(p0) | ((unsigned int)bfb(p1) << 16);
                    pw.y = (unsigned int)bfb(p2) | ((unsigned int)bfb(p3) << 16);
                    *(uint2*)(PB + q32 * 128 + ((i * 32 + g * 8) ^ rswz)) = pw;
                }
                ls += __shfl_xor(ls, 16);
                ls += __shfl_xor(ls, 32);
                l_[j] = l_[j] * fac + ls;
                if (g == 0) sA[wv * 32 + q32] = fac;
            }

#pragma unroll
            for (int iq = 0; iq < 2; iq++) {
                f32x4 fc = *(const f32x4*)&sA[wv * 32 + iq * 16 + g * 4];
#pragma unroll
                for (int jd = 0; jd < 4; jd++)
#pragma unroll
                    for (int r = 0; r < 4; r++) o_[iq][jd][r] *= fc[r];
            }
            __builtin_amdgcn_s_setprio(1);
#pragma unroll
            for (int kk = 0; kk < 2; kk++) {
                bf16x8 pa[2], vb[4];
#pragma unroll
                for (int iq = 0; iq < 2; iq++)
                    pa[iq] = *(const bf16x8*)(PB + (iq * 16 + l15) * 128 + ((kk * 64 + g * 16) ^ rswz));
#pragma unroll
                for (int jd = 0; jd < 4; jd++)
                    vb[jd] = *(const bf16x8*)(VT + (jd * 16 + l15) * 128 + ((kk * 64 + g * 16) ^ rswz));
#pragma unroll
                for (int iq = 0; iq < 2; iq++)
#pragma unroll
                    for (int jd = 0; jd < 4; jd++)
                        o_[iq][jd] = __builtin_amdgcn_mfma_f32_16x16x32_bf16(pa[iq], vb[jd], o_[iq][jd], 0, 0, 0);
            }
            __builtin_amdgcn_s_setprio(0);
        }

        asm volatile("s_waitcnt vmcnt(0)" ::: "memory");
        __builtin_amdgcn_sched_barrier(0);
        __builtin_amdgcn_s_barrier();
        __builtin_amdgcn_sched_barrier(0);
        cur ^= 1;
    }

#pragma unroll
    for (int j = 0; j < 2; j++) {
        float pd = 0.f;
#pragma unroll
        for (int kk = 0; kk < 2; kk++)
#pragma unroll
            for (int e = 0; e < 8; e++)
                pd += bf2f((unsigned short)qf[j][kk][e]) * bf2f((unsigned short)gkf[kk][e]);
        pd += __shfl_xor(pd, 16);
        pd += __shfl_xor(pd, 32);
        float sg = pd * 0.125f;
        float mf = fmaxf(m_[j], sg);
        float fac = __expf(m_[j] - mf);
        float pg = __expf(sg - mf);
        float lf = l_[j] * fac + pg;
        float inv = 1.f / lf;
        if (g == 0) {
            sA[wv * 32 + j * 16 + l15] = fac * inv;
            sB[wv * 32 + j * 16 + l15] = pg * inv;
        }
    }
#pragma unroll
    for (int iq = 0; iq < 2; iq++) {
        f32x4 fA = *(const f32x4*)&sA[wv * 32 + iq * 16 + g * 4];
        f32x4 fB = *(const f32x4*)&sB[wv * 32 + iq * 16 + g * 4];
#pragma unroll
        for (int jd = 0; jd < 4; jd++) {
#pragma unroll
            for (int r = 0; r < 4; r++) {
                float val = o_[iq][jd][r] * fA[r] + fB[r] * v0r[jd];
                int row = b * SS + q0 + wv * 32 + iq * 16 + g * 4 + r;
                O[(size_t)row * DD + h * 64 + jd * 16 + l15] = bfb(val);
            }
        }
    }
}

// ---------------- global-token attention, phase 1 ----------------
__global__ __launch_bounds__(256) void gattn1_k(const float* __restrict__ qg,
        const unsigned short* __restrict__ packed, const int* __restrict__ mask,
        float* __restrict__ pm, float* __restrict__ pl, float* __restrict__ po)
{
    int cc = blockIdx.x, h = blockIdx.y, b = blockIdx.z;
    int tid = threadIdx.x;
    __shared__ float qs[64], red[256], ps[256], ored[4][64];
    if (tid < 64) qs[tid] = qg[b * DD + h * 64 + tid];
    __syncthreads();
    int s = cc * 256 + tid;
    const unsigned short* kr = packed + (size_t)(b * SS + s) * 3840 + 3 * DD + h * 64;
    float a = 0.f;
#pragma unroll
    for (int d8 = 0; d8 < 8; d8++) {
        bf16x8 kv = *(const bf16x8*)(kr + d8 * 8);
#pragma unroll
        for (int e = 0; e < 8; e++)
            a = fmaf(qs[d8 * 8 + e], bf2f((unsigned short)kv[e]), a);
    }
    a *= 0.125f;
    float sv = (mask[b * SS + s] > 0) ? a : -1e9f;
    red[tid] = sv; __syncthreads();
    for (int o = 128; o > 0; o >>= 1) {
        if (tid < o) red[tid] = fmaxf(red[tid], red[tid + o]);
        __syncthreads();
    }
    float mx = red[0]; __syncthreads();
    float p = __expf(sv - mx);
    ps[tid] = p;
    red[tid] = p; __syncthreads();
    for (int o = 128; o > 0; o >>= 1) {
        if (tid < o) red[tid] += red[tid + o];
        __syncthreads();
    }
    float ls = red[0];
    int d = tid & 63, grp = tid >> 6;
    const unsigned short* vgb = packed + 4 * DD + h * 64 + d;
    float oa = 0.f;
    for (int t = 0; t < 64; t++) {
        int srow = cc * 256 + grp * 64 + t;
        oa = fmaf(ps[grp * 64 + t], bf2f(vgb[(size_t)(b * SS + srow) * 3840]), oa);
    }
    ored[grp][d] = oa; __syncthreads();
    if (tid < 64) {
        int idx = (b * HH + h) * 16 + cc;
        po[(size_t)idx * 64 + tid] = ored[0][tid] + ored[1][tid] + ored[2][tid] + ored[3][tid];
        if (tid == 0) { pm[idx] = mx; pl[idx] = ls; }
    }
}

// ---------------- global-token attention, phase 2 ----------------
__global__ __launch_bounds__(64) void gattn2_k(const float* __restrict__ pm,
        const float* __restrict__ pl, const float* __restrict__ po,
        unsigned short* __restrict__ O)
{
    int h = blockIdx.x, b = blockIdx.y;
    int tid = threadIdx.x;
    int base = (b * HH + h) * 16;
    float mx = -1e30f;
    for (int c2 = 0; c2 < 16; c2++) mx = fmaxf(mx, pm[base + c2]);
    float den = 0.f, oa = 0.f;
    for (int c2 = 0; c2 < 16; c2++) {
        float w = __expf(pm[base + c2] - mx);
        den = fmaf(pl[base + c2], w, den);
        oa = fmaf(po[(size_t)(base + c2) * 64 + tid], w, oa);
    }
    O[(size_t)(b * SS) * DD + h * 64 + tid] = bfb(oa / den);
}

// ---------------- row-GEMV (bf16 activations) ----------------
template<int ACT_TANH>
__global__ __launch_bounds__(256) void rowgemv_k(const unsigned short* __restrict__ x,
        size_t xstride, const float* __restrict__ W, const float* __restrict__ bias,
        float* __restrict__ dst, int N)
{
    int b = blockIdx.y;
    int colL = threadIdx.x & 63, part = threadIdx.x >> 6;
    int col = blockIdx.x * 64 + colL;
    __shared__ float partial[4][64];
    const unsigned short* xr = x + (size_t)b * xstride;
    float a = 0.f;
    for (int k = part * (DD / 4); k < (part + 1) * (DD / 4); k++)
        a = fmaf(bf2f(xr[k]), W[(size_t)k * N + col], a);
    partial[part][colL] = a; __syncthreads();
    if (part == 0) {
        float s = partial[0][colL] + partial[1][colL] + partial[2][colL] + partial[3][colL]
                + bias[col];
        if (ACT_TANH) s = tanhf(s);
        dst[b * N + col] = s;
    }
}

// ---------------- classifier ----------------
__global__ __launch_bounds__(256) void cls_k(const float* __restrict__ pooled,
        const float* __restrict__ Wc, const float* __restrict__ bc,
        float* __restrict__ out)
{
    int lane = threadIdx.x & 63, pair = threadIdx.x >> 6;
    int b = pair >> 1, cls = pair & 1;
    float a = 0.f;
#pragma unroll
    for (int j = 0; j < 12; j++) {
        int k = lane + j * 64;
        a = fmaf(pooled[b * DD + k], Wc[k * 2 + cls], a);
    }
#pragma unroll
    for (int o = 1; o < 64; o <<= 1) a += __shfl_xor(a, o);
    if (lane == 0) out[b * 2 + cls] = a + bc[cls];
}

extern "C" void kernel_launch(void* const* d_in, const int* in_sizes, int n_in,
                              void* d_out, int out_size, void* d_ws, size_t ws_size,
                              hipStream_t stream) {
    const int*   input_ids = (const int*)d_in[0];
    const int*   amask     = (const int*)d_in[1];
    const float* word_emb  = (const float*)d_in[2];
    const float* pos_emb   = (const float*)d_in[3];
    const float* ln_e_g    = (const float*)d_in[4];
    const float* ln_e_b    = (const float*)d_in[5];
    const float* Wq  = (const float*)d_in[6];  const float* bq  = (const float*)d_in[7];
    const float* Wk  = (const float*)d_in[8];  const float* bk  = (const float*)d_in[9];
    const float* Wv  = (const float*)d_in[10]; const float* bv  = (const float*)d_in[11];
    const float* Wqg = (const float*)d_in[12]; const float* bqg = (const float*)d_in[13];
    const float* Wkg = (const float*)d_in[14]; const float* bkg = (const float*)d_in[15];
    const float* Wvg = (const float*)d_in[16]; const float* bvg = (const float*)d_in[17];
    const float* Wo  = (const float*)d_in[18]; const float* bo  = (const float*)d_in[19];
    const float* ln1_g = (const float*)d_in[20]; const float* ln1_b = (const float*)d_in[21];
    const float* W1  = (const float*)d_in[22]; const float* bf1 = (const float*)d_in[23];
    const float* W2  = (const float*)d_in[24]; const float* bf2 = (const float*)d_in[25];
    const float* ln2_g = (const float*)d_in[26]; const float* ln2_b = (const float*)d_in[27];
    const float* Wp  = (const float*)d_in[28]; const float* bp  = (const float*)d_in[29];
    const float* Wc  = (const float*)d_in[30]; const float* bc  = (const float*)d_in[31];
    float* out = (float*)d_out;

    char* wsb = (char*)d_ws;
    unsigned short* xbf    = (unsigned short*)(wsb + 25165824);
    unsigned short* packed = (unsigned short*)(wsb + 37748736);
    unsigned short* vtb    = (unsigned short*)(wsb + 100663296);
    unsigned short* aout   = (unsigned short*)(wsb + 113246208);
    float*          hf     = (float*)(wsb + 125829120);
    char*           wts    = wsb + 150994944;
    float*          b5     = (float*)(wsb + 184025088);
    float*          qg     = (float*)(wsb + 184055808);
    float*          pm     = (float*)(wsb + 184061952);
    float*          pl     = (float*)(wsb + 184063488);
    float*          po     = (float*)(wsb + 184065024);
    float*          pooled = (float*)(wsb + 184163328);
    unsigned short* mid    = packed;

    const size_t SQ = (size_t)DD * DD;
    const size_t PER_L = (6 * SQ + 2 * (size_t)DD * FF) * 2;
    unsigned short* Wt5[2], *Wo_t[2], *W1_t[2], *W2_t[2];
    for (int l = 0; l < 2; l++) {
        char* base = wts + (size_t)l * PER_L;
        Wt5[l]  = (unsigned short*)base;
        Wo_t[l] = (unsigned short*)(base + 5 * SQ * 2);
        W1_t[l] = (unsigned short*)(base + 6 * SQ * 2);
        W2_t[l] = (unsigned short*)(base + 6 * SQ * 2 + (size_t)DD * FF * 2);
    }

    const int M = BB * SS;

    TP12 t12;
    for (int l = 0; l < 2; l++) {
        t12.s[l * 6 + 0] = Wq  + (size_t)l * SQ;  t12.d[l * 6 + 0] = Wt5[l] + 0 * SQ;
        t12.s[l * 6 + 1] = Wk  + (size_t)l * SQ;  t12.d[l * 6 + 1] = Wt5[l] + 1 * SQ;
        t12.s[l * 6 + 2] = Wv  + (size_t)l * SQ;  t12.d[l * 6 + 2] = Wt5[l] + 2 * SQ;
        t12.s[l * 6 + 3] = Wkg + (size_t)l * SQ;  t12.d[l * 6 + 3] = Wt5[l] + 3 * SQ;
        t12.s[l * 6 + 4] = Wvg + (size_t)l * SQ;  t12.d[l * 6 + 4] = Wt5[l] + 4 * SQ;
        t12.s[l * 6 + 5] = Wo  + (size_t)l * SQ;  t12.d[l * 6 + 5] = Wo_t[l];
    }
    TP4 t4;
    t4.s[0] = W1;                      t4.d[0] = W1_t[0];
    t4.s[1] = W1 + (size_t)DD * FF;    t4.d[1] = W1_t[1];
    t4.s[2] = W2;                      t4.d[2] = W2_t[0];
    t4.s[3] = W2 + (size_t)FF * DD;    t4.d[3] = W2_t[1];

    transpose12_k<<<dim3(24, 24, 12), 256, 0, stream>>>(t12);
    transposeR4_k<<<dim3(96, 24, 4), 256, 0, stream>>>(t4);
    pack_bias5_k<<<(2 * 5 * DD + 255) / 256, 256, 0, stream>>>(bq, bk, bv, bkg, bvg, b5);

    embed_ln_k<<<M, 256, 0, stream>>>(input_ids, word_emb, pos_emb, ln_e_g, ln_e_b, xbf);

    dim3 gqkv(M / 128, 3840 / 128);               // (64, 30)
    dim3 g768(M / 128, DD / 128);                 // (64, 6)
    dim3 g3072(M / 128, FF / 128);                // (64, 24)

    for (int l = 0; l < 2; l++) {
        const float* Wqg_l = Wqg + (size_t)l * SQ; const float* bqg_l = bqg + (size_t)l * DD;
        const float* bo_l  = bo  + (size_t)l * DD;
        const float* bf1_l = bf1 + (size_t)l * FF;
        const float* bf2_l = bf2 + (size_t)l * DD;
        const float* g1_l  = ln1_g + (size_t)l * DD; const float* b1_l = ln1_b + (size_t)l * DD;
        const float* g2_l  = ln2_g + (size_t)l * DD; const float* b2_l = ln2_b + (size_t)l * DD;

        // QKV GEMM with fused V head-transpose (V cols -> vtb; no vtrans kernel)
        mfma_gemm_k<1, 0, 0, 1><<<gqkv, 256, 0, stream>>>(xbf, Wt5[l], b5 + (size_t)l * 3840,
                                                          nullptr, vtb, packed, M, 3840, DD);
        rowgemv_k<0><<<dim3(DD / 64, BB), 256, 0, stream>>>(xbf, (size_t)SS * DD, Wqg_l, bqg_l, qg, DD);

        swin_mfma_k<<<dim3(SS / 128, HH, BB), 256, 0, stream>>>(packed, vtb, amask, aout);
        gattn1_k<<<dim3(16, HH, BB), 256, 0, stream>>>(qg, packed, amask, pm, pl, po);
        gattn2_k<<<dim3(HH, BB), 64, 0, stream>>>(pm, pl, po, aout);

        // h + x(bf16 residual) fused into epilogue; fp32 hf; ln_k normalizes
        mfma_gemm_k<0, 0, 1, 0><<<g768, 256, 0, stream>>>(aout, Wo_t[l], bo_l, xbf, nullptr, hf, M, DD, DD);
        ln_k<<<M, 256, 0, stream>>>(hf, g1_l, b1_l, xbf);

        mfma_gemm_k<1, 1, 0, 0><<<g3072, 256, 0, stream>>>(xbf, W1_t[l], bf1_l, nullptr, nullptr, mid, M, FF, DD);
        mfma_gemm_k<0, 0, 1, 0><<<g768, 256, 0, stream>>>(mid, W2_t[l], bf2_l, xbf, nullptr, hf, M, DD, FF);
        ln_k<<<M, 256, 0, stream>>>(hf, g2_l, b2_l, xbf);
    }

    rowgemv_k<1><<<dim3(DD / 64, BB), 256, 0, stream>>>(xbf, (size_t)SS * DD, Wp, bp, pooled, DD);
    cls_k<<<1, 256, 0, stream>>>(pooled, Wc, bc, out);
}